// Round 9
// baseline (188.048 us; speedup 1.0000x reference)
//
#include <hip/hip_runtime.h>
#include <hip/hip_bf16.h>

// MHA: B=2, T=2048, D=1024, H=16, DH=64. fp32 in/out, bf16 MFMA internal.
// R9: attn re-fetch fix — XCD-pinned heads (id%32 -> same XCD per head) and
//     shared K/V staging for paired chunks {p,31-p} in one k-loop (stage once,
//     compute both). GEMMs = R8 proven versions.

typedef __bf16 bf16x8 __attribute__((ext_vector_type(8)));
typedef __bf16 bf16x4 __attribute__((ext_vector_type(4)));
typedef float  f32x4  __attribute__((ext_vector_type(4)));

#define Bx 2
#define Tx 2048
#define Dx 1024
#define Hx 16
#define DHx 64

// ---------------- prep: z=0 -> x fp32->bf16; z=1..4 -> W transpose+cvt ----------------
__global__ __launch_bounds__(256) void prep(const float* __restrict__ x,
                                            const float* __restrict__ W0,
                                            const float* __restrict__ W1,
                                            const float* __restrict__ W2,
                                            const float* __restrict__ W3,
                                            __bf16* __restrict__ xb,
                                            __bf16* __restrict__ Wt) {
    const int z = blockIdx.z;
    if (z == 0) {
        const int blk = blockIdx.y * 16 + blockIdx.x;
        const float* xp = x + (size_t)blk * 16384;
        __bf16* xo = xb + (size_t)blk * 16384;
#pragma unroll
        for (int i = 0; i < 16; i++) {
            float4 v = *(const float4*)(xp + i * 1024 + threadIdx.x * 4);
            bf16x4 o;
            o[0] = (__bf16)v.x; o[1] = (__bf16)v.y; o[2] = (__bf16)v.z; o[3] = (__bf16)v.w;
            *(bf16x4*)(xo + i * 1024 + threadIdx.x * 4) = o;
        }
        return;
    }
    __shared__ float tile[64][65];
    const float* W = (z == 1) ? W0 : (z == 2) ? W1 : (z == 3) ? W2 : W3;
    __bf16* o = Wt + (size_t)(z - 1) * Dx * Dx;
    int k0 = blockIdx.x * 64, n0 = blockIdx.y * 64;
    int t = threadIdx.x;
    int cc = t & 63, rbase = t >> 6;
#pragma unroll
    for (int i = 0; i < 16; i++) {
        int rr = rbase + i * 4;
        tile[rr][cc] = W[(size_t)(k0 + rr) * Dx + n0 + cc];
    }
    __syncthreads();
#pragma unroll
    for (int i = 0; i < 16; i++) {
        int rr = rbase + i * 4;
        o[(size_t)(n0 + rr) * Dx + k0 + cc] = (__bf16)tile[cc][rr];
    }
}

static __device__ __forceinline__ void gload16(const __bf16* g, __bf16* l) {
    __builtin_amdgcn_global_load_lds((const __attribute__((address_space(1))) void*)g,
                                     (__attribute__((address_space(3))) void*)l, 16, 0, 0);
}

// ---------------- fused QKV GEMM: [4096 x 3072] = xb @ [WqT;WkT;WvT]^T ----------------
// 64x128 tile, BK=32. Grid 64x24 = 1536 blocks = 6/CU. Wave (wm,wn) computes 32x64.
__global__ __launch_bounds__(256, 6) void gemm_qkv(const __bf16* __restrict__ A,
                                                   const __bf16* __restrict__ BT,
                                                   __bf16* __restrict__ Qb,
                                                   __bf16* __restrict__ Kb,
                                                   __bf16* __restrict__ Vt) {
    __shared__ __bf16 As[64 * 32];   // 4 KB
    __shared__ __bf16 Bs[128 * 32];  // 8 KB
    const int t = threadIdx.x;
    const int lane = t & 63, wave = t >> 6;
    const int lane15 = lane & 15, quad = lane >> 4;
    const int m0 = blockIdx.x * 64, n0 = blockIdx.y * 128;
    const int wm = wave & 1, wn = wave >> 1;

    const int srA = wave * 16 + (lane >> 2), sc = (lane & 3) * 8;
    const int srB = wave * 32 + (lane >> 2);
    const __bf16* Ag = A + (size_t)(m0 + srA) * Dx + sc;
    const __bf16* Bg = BT + (size_t)(n0 + srB) * Dx + sc;
    __bf16* Asl  = As + (wave * 16) * 32;
    __bf16* Bsl0 = Bs + (wave * 32) * 32;
    __bf16* Bsl1 = Bs + (wave * 32 + 16) * 32;

    f32x4 acc[2][4];
#pragma unroll
    for (int i = 0; i < 2; i++)
#pragma unroll
        for (int j = 0; j < 4; j++) acc[i][j] = (f32x4){0.f, 0.f, 0.f, 0.f};

    for (int k0 = 0; k0 < Dx; k0 += 32) {
        gload16(Ag, Asl);
        gload16(Bg, Bsl0);
        gload16(Bg + 16 * Dx, Bsl1);
        Ag += 32; Bg += 32;
        __syncthreads();
        bf16x8 af[2], bf[4];
#pragma unroll
        for (int i = 0; i < 2; i++)
            af[i] = *(const bf16x8*)&As[(wm * 32 + i * 16 + lane15) * 32 + quad * 8];
#pragma unroll
        for (int j = 0; j < 4; j++)
            bf[j] = *(const bf16x8*)&Bs[(wn * 64 + j * 16 + lane15) * 32 + quad * 8];
#pragma unroll
        for (int mt = 0; mt < 2; mt++)
#pragma unroll
            for (int nt = 0; nt < 4; nt++)
                acc[mt][nt] = __builtin_amdgcn_mfma_f32_16x16x32_bf16(af[mt], bf[nt], acc[mt][nt], 0, 0, 0);
        __syncthreads();
    }

    const int z = n0 >> 10;  // block n-range lies in one z (128 | 1024)
    if (z < 2) {
        __bf16* outp = z ? Kb : Qb;
        const float scale = z ? 1.0f : 0.125f;
#pragma unroll
        for (int mt = 0; mt < 2; mt++)
#pragma unroll
            for (int nt = 0; nt < 4; nt++) {
                const int cc = (n0 + wn * 64 + nt * 16 + lane15) & 1023;
                const int h = cc >> 6, dh = cc & 63;
#pragma unroll
                for (int r4 = 0; r4 < 4; r4++) {
                    const int row = m0 + wm * 32 + mt * 16 + quad * 4 + r4;
                    const int b = row >> 11, tt = row & 2047;
                    outp[(((size_t)(b * Hx + h) * Tx + tt) << 6) + dh] =
                        (__bf16)(acc[mt][nt][r4] * scale);
                }
            }
    } else {
#pragma unroll
        for (int mt = 0; mt < 2; mt++)
#pragma unroll
            for (int nt = 0; nt < 4; nt++) {
                const int cc = (n0 + wn * 64 + nt * 16 + lane15) & 1023;
                const int h = cc >> 6, dh = cc & 63;
#pragma unroll
                for (int r4 = 0; r4 < 4; r4++) {
                    const int row = m0 + wm * 32 + mt * 16 + quad * 4 + r4;
                    const int b = row >> 11, tt = row & 2047;
                    Vt[((size_t)(b * Hx + h) * DHx + dh) * Tx + tt] = (__bf16)acc[mt][nt][r4];
                }
            }
    }
}

// ---------------- output GEMM: out[4096 x 1024] = ctx @ Wo + bo ----------------
// 64x64 tile. Grid 64x16 = 1024 blocks = 4/CU. Wave (wm,wn) computes 32x32.
__global__ __launch_bounds__(256, 4) void gemm_out(const __bf16* __restrict__ A,
                                                   const __bf16* __restrict__ BT,
                                                   float* __restrict__ outf,
                                                   const float* __restrict__ bias) {
    __shared__ __bf16 As[64 * 32];
    __shared__ __bf16 Bs[64 * 32];
    const int t = threadIdx.x;
    const int lane = t & 63, wave = t >> 6;
    const int lane15 = lane & 15, quad = lane >> 4;
    const int m0 = blockIdx.x * 64, n0 = blockIdx.y * 64;
    const int wm = wave & 1, wn = wave >> 1;

    const int sr = wave * 16 + (lane >> 2), sc = (lane & 3) * 8;
    const __bf16* Ag = A + (size_t)(m0 + sr) * Dx + sc;
    const __bf16* Bg = BT + (size_t)(n0 + sr) * Dx + sc;
    __bf16* Asl = As + (wave * 16) * 32;
    __bf16* Bsl = Bs + (wave * 16) * 32;

    f32x4 acc[2][2];
#pragma unroll
    for (int i = 0; i < 2; i++)
#pragma unroll
        for (int j = 0; j < 2; j++) acc[i][j] = (f32x4){0.f, 0.f, 0.f, 0.f};

    for (int k0 = 0; k0 < Dx; k0 += 32) {
        gload16(Ag, Asl);
        gload16(Bg, Bsl);
        Ag += 32; Bg += 32;
        __syncthreads();
        bf16x8 af[2], bf[2];
#pragma unroll
        for (int i = 0; i < 2; i++) {
            af[i] = *(const bf16x8*)&As[(wm * 32 + i * 16 + lane15) * 32 + quad * 8];
            bf[i] = *(const bf16x8*)&Bs[(wn * 32 + i * 16 + lane15) * 32 + quad * 8];
        }
#pragma unroll
        for (int mt = 0; mt < 2; mt++)
#pragma unroll
            for (int nt = 0; nt < 2; nt++)
                acc[mt][nt] = __builtin_amdgcn_mfma_f32_16x16x32_bf16(af[mt], bf[nt], acc[mt][nt], 0, 0, 0);
        __syncthreads();
    }

#pragma unroll
    for (int mt = 0; mt < 2; mt++)
#pragma unroll
        for (int nt = 0; nt < 2; nt++) {
            const int col = n0 + wn * 32 + nt * 16 + lane15;
#pragma unroll
            for (int r4 = 0; r4 < 4; r4++) {
                const int row = m0 + wm * 32 + mt * 16 + quad * 4 + r4;
                outf[(size_t)row * Dx + col] = acc[mt][nt][r4] + bias[col];
            }
        }
}

// ---------------- MFMA flash attention: XCD-pinned, shared-staging pair ----------------
// 1-D grid of 512: bh = id%32 (all 16 blocks of a head -> same XCD via id%8),
// pair p = id/32. One k-loop over tiles 0..31-p: hi=31-p computes every tile,
// lo=p computes tiles 0..p. Exactly 33 tile-computes per block (balanced).
// LDS dbuf K/V, one barrier per tile.
__global__ __launch_bounds__(256) void attn_mfma(const __bf16* __restrict__ Q,
                                                 const __bf16* __restrict__ K,
                                                 const __bf16* __restrict__ Vt,
                                                 __bf16* __restrict__ ctx) {
    __shared__ __bf16 Ks[2][64 * 72];   // [buf][key][d]
    __shared__ __bf16 Vs[2][64 * 72];   // [buf][d][key]
    __shared__ __bf16 Ps[64 * 80];      // [q][key]
    const int t = threadIdx.x;
    const int lane = t & 63, wave = t >> 6;
    const int lane15 = lane & 15, quad = lane >> 4;
    const int id = blockIdx.x;
    const int bh = id & 31, p = id >> 5;
    const int b = bh >> 4, h = bh & 15;
    const int lo = p, hi = 31 - p;
    const int ktiles = hi + 1;
    const size_t headoff = ((size_t)(b * Hx + h)) * Tx * DHx;
    const __bf16* Kbase = K + headoff;   // [t][d]
    const __bf16* Vbase = Vt + headoff;  // [d][t]
    const int sr = t >> 2, sc = (t & 3) * 16;  // staging: 64 rows x 4x16 cols

    // Q fragments for both chunks
    bf16x8 qh0, qh1, ql0, ql1;
    {
        const __bf16* Qp = Q + headoff + (size_t)(hi * 64 + wave * 16 + lane15) * 64 + quad * 8;
        qh0 = *(const bf16x8*)Qp; qh1 = *(const bf16x8*)(Qp + 32);
        const __bf16* Qp2 = Q + headoff + (size_t)(lo * 64 + wave * 16 + lane15) * 64 + quad * 8;
        ql0 = *(const bf16x8*)Qp2; ql1 = *(const bf16x8*)(Qp2 + 32);
    }
    f32x4 oh[4], ol[4];
#pragma unroll
    for (int i = 0; i < 4; i++) { oh[i] = (f32x4){0.f,0.f,0.f,0.f}; ol[i] = (f32x4){0.f,0.f,0.f,0.f}; }
    float lh[4] = {0.f,0.f,0.f,0.f}, ll[4] = {0.f,0.f,0.f,0.f};
    const int qgh = hi * 64 + wave * 16 + quad * 4;
    const int qgl = lo * 64 + wave * 16 + quad * 4;

    // prefetch tile 0 into regs
    bf16x8 kpre0, kpre1, vpre0, vpre1;
    {
        const __bf16* Kp = Kbase + (size_t)sr * 64 + sc;
        kpre0 = *(const bf16x8*)Kp; kpre1 = *(const bf16x8*)(Kp + 8);
        const __bf16* Vp = Vbase + (size_t)sr * Tx + sc;
        vpre0 = *(const bf16x8*)Vp; vpre1 = *(const bf16x8*)(Vp + 8);
    }

    for (int kt = 0; kt < ktiles; kt++) {
        const int cur = kt & 1;
        *(bf16x8*)&Ks[cur][sr * 72 + sc] = kpre0;
        *(bf16x8*)&Ks[cur][sr * 72 + sc + 8] = kpre1;
        *(bf16x8*)&Vs[cur][sr * 72 + sc] = vpre0;
        *(bf16x8*)&Vs[cur][sr * 72 + sc + 8] = vpre1;
        if (kt + 1 < ktiles) {
            const __bf16* Kp = Kbase + (size_t)((kt + 1) * 64 + sr) * 64 + sc;
            kpre0 = *(const bf16x8*)Kp; kpre1 = *(const bf16x8*)(Kp + 8);
            const __bf16* Vp = Vbase + (size_t)sr * Tx + (kt + 1) * 64 + sc;
            vpre0 = *(const bf16x8*)Vp; vpre1 = *(const bf16x8*)(Vp + 8);
        }
        __syncthreads();  // the only barrier per tile

        const int kbase = kt * 64;

        // ---------- hi chunk (every tile) ----------
        {
            f32x4 s[4];
#pragma unroll
            for (int nt = 0; nt < 4; nt++) {
                s[nt] = (f32x4){0.f, 0.f, 0.f, 0.f};
                bf16x8 b0 = *(const bf16x8*)&Ks[cur][(nt * 16 + lane15) * 72 + quad * 8];
                s[nt] = __builtin_amdgcn_mfma_f32_16x16x32_bf16(qh0, b0, s[nt], 0, 0, 0);
                bf16x8 b1 = *(const bf16x8*)&Ks[cur][(nt * 16 + lane15) * 72 + 32 + quad * 8];
                s[nt] = __builtin_amdgcn_mfma_f32_16x16x32_bf16(qh1, b1, s[nt], 0, 0, 0);
            }
#pragma unroll
            for (int nt = 0; nt < 4; nt++)
#pragma unroll
                for (int reg = 0; reg < 4; reg++) {
                    float e = __expf(s[nt][reg]);
                    if (kbase + nt * 16 + lane15 > qgh + reg) e = 0.f;
                    lh[reg] += e;
                    Ps[(wave * 16 + quad * 4 + reg) * 80 + nt * 16 + lane15] = (__bf16)e;
                }
            bf16x8 pa0 = *(const bf16x8*)&Ps[(wave * 16 + lane15) * 80 + quad * 8];
            bf16x8 pa1 = *(const bf16x8*)&Ps[(wave * 16 + lane15) * 80 + 32 + quad * 8];
#pragma unroll
            for (int dt = 0; dt < 4; dt++) {
                bf16x8 vb0 = *(const bf16x8*)&Vs[cur][(dt * 16 + lane15) * 72 + quad * 8];
                oh[dt] = __builtin_amdgcn_mfma_f32_16x16x32_bf16(pa0, vb0, oh[dt], 0, 0, 0);
                bf16x8 vb1 = *(const bf16x8*)&Vs[cur][(dt * 16 + lane15) * 72 + 32 + quad * 8];
                oh[dt] = __builtin_amdgcn_mfma_f32_16x16x32_bf16(pa1, vb1, oh[dt], 0, 0, 0);
            }
        }

        // ---------- lo chunk (tiles 0..p) ----------
        if (kt <= lo) {
            f32x4 s[4];
#pragma unroll
            for (int nt = 0; nt < 4; nt++) {
                s[nt] = (f32x4){0.f, 0.f, 0.f, 0.f};
                bf16x8 b0 = *(const bf16x8*)&Ks[cur][(nt * 16 + lane15) * 72 + quad * 8];
                s[nt] = __builtin_amdgcn_mfma_f32_16x16x32_bf16(ql0, b0, s[nt], 0, 0, 0);
                bf16x8 b1 = *(const bf16x8*)&Ks[cur][(nt * 16 + lane15) * 72 + 32 + quad * 8];
                s[nt] = __builtin_amdgcn_mfma_f32_16x16x32_bf16(ql1, b1, s[nt], 0, 0, 0);
            }
#pragma unroll
            for (int nt = 0; nt < 4; nt++)
#pragma unroll
                for (int reg = 0; reg < 4; reg++) {
                    float e = __expf(s[nt][reg]);
                    if (kbase + nt * 16 + lane15 > qgl + reg) e = 0.f;
                    ll[reg] += e;
                    Ps[(wave * 16 + quad * 4 + reg) * 80 + nt * 16 + lane15] = (__bf16)e;
                }
            bf16x8 pa0 = *(const bf16x8*)&Ps[(wave * 16 + lane15) * 80 + quad * 8];
            bf16x8 pa1 = *(const bf16x8*)&Ps[(wave * 16 + lane15) * 80 + 32 + quad * 8];
#pragma unroll
            for (int dt = 0; dt < 4; dt++) {
                bf16x8 vb0 = *(const bf16x8*)&Vs[cur][(dt * 16 + lane15) * 72 + quad * 8];
                ol[dt] = __builtin_amdgcn_mfma_f32_16x16x32_bf16(pa0, vb0, ol[dt], 0, 0, 0);
                bf16x8 vb1 = *(const bf16x8*)&Vs[cur][(dt * 16 + lane15) * 72 + 32 + quad * 8];
                ol[dt] = __builtin_amdgcn_mfma_f32_16x16x32_bf16(pa1, vb1, ol[dt], 0, 0, 0);
            }
        }
    }

    // epilogue: both chunks
#pragma unroll
    for (int reg = 0; reg < 4; reg++) {
        float a = lh[reg], c = ll[reg];
#pragma unroll
        for (int off = 1; off < 16; off <<= 1) {
            a += __shfl_xor(a, off);
            c += __shfl_xor(c, off);
        }
        lh[reg] = 1.f / a;
        ll[reg] = 1.f / c;
    }
#pragma unroll
    for (int dt = 0; dt < 4; dt++)
#pragma unroll
        for (int reg = 0; reg < 4; reg++) {
            int qh = hi * 64 + wave * 16 + quad * 4 + reg;
            ctx[(((size_t)(b * Tx + qh)) * Hx + h) * 64 + dt * 16 + lane15] =
                (__bf16)(oh[dt][reg] * lh[reg]);
            int ql = lo * 64 + wave * 16 + quad * 4 + reg;
            ctx[(((size_t)(b * Tx + ql)) * Hx + h) * 64 + dt * 16 + lane15] =
                (__bf16)(ol[dt][reg] * ll[reg]);
        }
}

extern "C" void kernel_launch(void* const* d_in, const int* in_sizes, int n_in,
                              void* d_out, int out_size, void* d_ws, size_t ws_size,
                              hipStream_t stream) {
    const float* x  = (const float*)d_in[0];
    const float* Wq = (const float*)d_in[1];
    const float* Wk = (const float*)d_in[2];
    const float* Wv = (const float*)d_in[3];
    const float* Wo = (const float*)d_in[4];
    const float* bo = (const float*)d_in[5];
    float* out = (float*)d_out;

    char* ws = (char*)d_ws;
    __bf16* xb  = (__bf16*)(ws + 0);                 // 8 MB
    __bf16* Wt  = (__bf16*)(ws + (8ull << 20));      // 4 x 2 MB
    __bf16* Qb  = (__bf16*)(ws + (16ull << 20));     // 8 MB [B,H,T,DH] (pre-scaled 1/8)
    __bf16* Kb  = (__bf16*)(ws + (24ull << 20));     // 8 MB [B,H,T,DH]
    __bf16* Vtg = (__bf16*)(ws + (32ull << 20));     // 8 MB [B,H,DH,T]
    __bf16* ctx = (__bf16*)(ws + (40ull << 20));     // 8 MB [B,T,H,DH]

    prep<<<dim3(16, 16, 5), 256, 0, stream>>>(x, Wq, Wk, Wv, Wo, xb, Wt);

    gemm_qkv<<<dim3(Bx * Tx / 64, 3 * Dx / 128), 256, 0, stream>>>(xb, Wt, Qb, Kb, Vtg);

    attn_mfma<<<dim3(512), 256, 0, stream>>>(Qb, Kb, Vtg, ctx);

    gemm_out<<<dim3(Bx * Tx / 64, Dx / 64), 256, 0, stream>>>(ctx, Wt + 3 * (1u << 20), out, bo);
}

// Round 10
// 185.007 us; speedup vs baseline: 1.0164x; 1.0164x over previous
//
#include <hip/hip_runtime.h>
#include <hip/hip_bf16.h>

// MHA: B=2, T=2048, D=1024, H=16, DH=64. fp32 in/out, bf16 MFMA internal.
// R10: attn concurrency fix — un-paired chunks (1024 blocks = 4/CU, longest
//      first), single-buffer LDS (28 KB), XCD-pinned heads kept (R9's fetch fix).
//      GEMMs/prep = R8 proven versions.

typedef __bf16 bf16x8 __attribute__((ext_vector_type(8)));
typedef __bf16 bf16x4 __attribute__((ext_vector_type(4)));
typedef float  f32x4  __attribute__((ext_vector_type(4)));

#define Bx 2
#define Tx 2048
#define Dx 1024
#define Hx 16
#define DHx 64

// ---------------- prep: z=0 -> x fp32->bf16; z=1..4 -> W transpose+cvt ----------------
__global__ __launch_bounds__(256) void prep(const float* __restrict__ x,
                                            const float* __restrict__ W0,
                                            const float* __restrict__ W1,
                                            const float* __restrict__ W2,
                                            const float* __restrict__ W3,
                                            __bf16* __restrict__ xb,
                                            __bf16* __restrict__ Wt) {
    const int z = blockIdx.z;
    if (z == 0) {
        const int blk = blockIdx.y * 16 + blockIdx.x;
        const float* xp = x + (size_t)blk * 16384;
        __bf16* xo = xb + (size_t)blk * 16384;
#pragma unroll
        for (int i = 0; i < 16; i++) {
            float4 v = *(const float4*)(xp + i * 1024 + threadIdx.x * 4);
            bf16x4 o;
            o[0] = (__bf16)v.x; o[1] = (__bf16)v.y; o[2] = (__bf16)v.z; o[3] = (__bf16)v.w;
            *(bf16x4*)(xo + i * 1024 + threadIdx.x * 4) = o;
        }
        return;
    }
    __shared__ float tile[64][65];
    const float* W = (z == 1) ? W0 : (z == 2) ? W1 : (z == 3) ? W2 : W3;
    __bf16* o = Wt + (size_t)(z - 1) * Dx * Dx;
    int k0 = blockIdx.x * 64, n0 = blockIdx.y * 64;
    int t = threadIdx.x;
    int cc = t & 63, rbase = t >> 6;
#pragma unroll
    for (int i = 0; i < 16; i++) {
        int rr = rbase + i * 4;
        tile[rr][cc] = W[(size_t)(k0 + rr) * Dx + n0 + cc];
    }
    __syncthreads();
#pragma unroll
    for (int i = 0; i < 16; i++) {
        int rr = rbase + i * 4;
        o[(size_t)(n0 + rr) * Dx + k0 + cc] = (__bf16)tile[cc][rr];
    }
}

static __device__ __forceinline__ void gload16(const __bf16* g, __bf16* l) {
    __builtin_amdgcn_global_load_lds((const __attribute__((address_space(1))) void*)g,
                                     (__attribute__((address_space(3))) void*)l, 16, 0, 0);
}

// ---------------- fused QKV GEMM: [4096 x 3072] = xb @ [WqT;WkT;WvT]^T ----------------
// 64x128 tile, BK=32. Grid 64x24 = 1536 blocks = 6/CU. Wave (wm,wn) computes 32x64.
__global__ __launch_bounds__(256, 6) void gemm_qkv(const __bf16* __restrict__ A,
                                                   const __bf16* __restrict__ BT,
                                                   __bf16* __restrict__ Qb,
                                                   __bf16* __restrict__ Kb,
                                                   __bf16* __restrict__ Vt) {
    __shared__ __bf16 As[64 * 32];   // 4 KB
    __shared__ __bf16 Bs[128 * 32];  // 8 KB
    const int t = threadIdx.x;
    const int lane = t & 63, wave = t >> 6;
    const int lane15 = lane & 15, quad = lane >> 4;
    const int m0 = blockIdx.x * 64, n0 = blockIdx.y * 128;
    const int wm = wave & 1, wn = wave >> 1;

    const int srA = wave * 16 + (lane >> 2), sc = (lane & 3) * 8;
    const int srB = wave * 32 + (lane >> 2);
    const __bf16* Ag = A + (size_t)(m0 + srA) * Dx + sc;
    const __bf16* Bg = BT + (size_t)(n0 + srB) * Dx + sc;
    __bf16* Asl  = As + (wave * 16) * 32;
    __bf16* Bsl0 = Bs + (wave * 32) * 32;
    __bf16* Bsl1 = Bs + (wave * 32 + 16) * 32;

    f32x4 acc[2][4];
#pragma unroll
    for (int i = 0; i < 2; i++)
#pragma unroll
        for (int j = 0; j < 4; j++) acc[i][j] = (f32x4){0.f, 0.f, 0.f, 0.f};

    for (int k0 = 0; k0 < Dx; k0 += 32) {
        gload16(Ag, Asl);
        gload16(Bg, Bsl0);
        gload16(Bg + 16 * Dx, Bsl1);
        Ag += 32; Bg += 32;
        __syncthreads();
        bf16x8 af[2], bf[4];
#pragma unroll
        for (int i = 0; i < 2; i++)
            af[i] = *(const bf16x8*)&As[(wm * 32 + i * 16 + lane15) * 32 + quad * 8];
#pragma unroll
        for (int j = 0; j < 4; j++)
            bf[j] = *(const bf16x8*)&Bs[(wn * 64 + j * 16 + lane15) * 32 + quad * 8];
#pragma unroll
        for (int mt = 0; mt < 2; mt++)
#pragma unroll
            for (int nt = 0; nt < 4; nt++)
                acc[mt][nt] = __builtin_amdgcn_mfma_f32_16x16x32_bf16(af[mt], bf[nt], acc[mt][nt], 0, 0, 0);
        __syncthreads();
    }

    const int z = n0 >> 10;  // block n-range lies in one z (128 | 1024)
    if (z < 2) {
        __bf16* outp = z ? Kb : Qb;
        const float scale = z ? 1.0f : 0.125f;
#pragma unroll
        for (int mt = 0; mt < 2; mt++)
#pragma unroll
            for (int nt = 0; nt < 4; nt++) {
                const int cc = (n0 + wn * 64 + nt * 16 + lane15) & 1023;
                const int h = cc >> 6, dh = cc & 63;
#pragma unroll
                for (int r4 = 0; r4 < 4; r4++) {
                    const int row = m0 + wm * 32 + mt * 16 + quad * 4 + r4;
                    const int b = row >> 11, tt = row & 2047;
                    outp[(((size_t)(b * Hx + h) * Tx + tt) << 6) + dh] =
                        (__bf16)(acc[mt][nt][r4] * scale);
                }
            }
    } else {
#pragma unroll
        for (int mt = 0; mt < 2; mt++)
#pragma unroll
            for (int nt = 0; nt < 4; nt++) {
                const int cc = (n0 + wn * 64 + nt * 16 + lane15) & 1023;
                const int h = cc >> 6, dh = cc & 63;
#pragma unroll
                for (int r4 = 0; r4 < 4; r4++) {
                    const int row = m0 + wm * 32 + mt * 16 + quad * 4 + r4;
                    const int b = row >> 11, tt = row & 2047;
                    Vt[((size_t)(b * Hx + h) * DHx + dh) * Tx + tt] = (__bf16)acc[mt][nt][r4];
                }
            }
    }
}

// ---------------- output GEMM: out[4096 x 1024] = ctx @ Wo + bo ----------------
// 64x64 tile. Grid 64x16 = 1024 blocks = 4/CU. Wave (wm,wn) computes 32x32.
__global__ __launch_bounds__(256, 4) void gemm_out(const __bf16* __restrict__ A,
                                                   const __bf16* __restrict__ BT,
                                                   float* __restrict__ outf,
                                                   const float* __restrict__ bias) {
    __shared__ __bf16 As[64 * 32];
    __shared__ __bf16 Bs[64 * 32];
    const int t = threadIdx.x;
    const int lane = t & 63, wave = t >> 6;
    const int lane15 = lane & 15, quad = lane >> 4;
    const int m0 = blockIdx.x * 64, n0 = blockIdx.y * 64;
    const int wm = wave & 1, wn = wave >> 1;

    const int sr = wave * 16 + (lane >> 2), sc = (lane & 3) * 8;
    const __bf16* Ag = A + (size_t)(m0 + sr) * Dx + sc;
    const __bf16* Bg = BT + (size_t)(n0 + sr) * Dx + sc;
    __bf16* Asl = As + (wave * 16) * 32;
    __bf16* Bsl = Bs + (wave * 16) * 32;

    f32x4 acc[2][2];
#pragma unroll
    for (int i = 0; i < 2; i++)
#pragma unroll
        for (int j = 0; j < 2; j++) acc[i][j] = (f32x4){0.f, 0.f, 0.f, 0.f};

    for (int k0 = 0; k0 < Dx; k0 += 32) {
        gload16(Ag, Asl);
        gload16(Bg, Bsl);
        Ag += 32; Bg += 32;
        __syncthreads();
        bf16x8 af[2], bf[2];
#pragma unroll
        for (int i = 0; i < 2; i++) {
            af[i] = *(const bf16x8*)&As[(wm * 32 + i * 16 + lane15) * 32 + quad * 8];
            bf[i] = *(const bf16x8*)&Bs[(wn * 32 + i * 16 + lane15) * 32 + quad * 8];
        }
#pragma unroll
        for (int mt = 0; mt < 2; mt++)
#pragma unroll
            for (int nt = 0; nt < 2; nt++)
                acc[mt][nt] = __builtin_amdgcn_mfma_f32_16x16x32_bf16(af[mt], bf[nt], acc[mt][nt], 0, 0, 0);
        __syncthreads();
    }

#pragma unroll
    for (int mt = 0; mt < 2; mt++)
#pragma unroll
        for (int nt = 0; nt < 2; nt++) {
            const int col = n0 + wn * 32 + nt * 16 + lane15;
#pragma unroll
            for (int r4 = 0; r4 < 4; r4++) {
                const int row = m0 + wm * 32 + mt * 16 + quad * 4 + r4;
                outf[(size_t)row * Dx + col] = acc[mt][nt][r4] + bias[col];
            }
        }
}

// ---------------- MFMA flash attention: 1 chunk/block, 4/CU, XCD-pinned ----------------
// Grid 1024 = 32 chunk-slots x 32 (b,h). id%32 = bh -> same-head blocks share an XCD
// (id%8 const); id/32 = ord, chunk = 31-ord -> longest blocks dispatch first.
// All 1024 blocks co-resident (28 KB LDS, 4/CU): imbalance absorbed by TLP.
// Single-buffer K/V, 2 barriers/tile; register prefetch of next tile.
__global__ __launch_bounds__(256) void attn_mfma(const __bf16* __restrict__ Q,
                                                 const __bf16* __restrict__ K,
                                                 const __bf16* __restrict__ Vt,
                                                 __bf16* __restrict__ ctx) {
    __shared__ __bf16 Ks[64 * 72];   // [key][d]   9 KB
    __shared__ __bf16 Vs[64 * 72];   // [d][key]   9 KB
    __shared__ __bf16 Ps[64 * 80];   // [q][key]  10 KB
    const int t = threadIdx.x;
    const int lane = t & 63, wave = t >> 6;
    const int lane15 = lane & 15, quad = lane >> 4;
    const int id = blockIdx.x;
    const int bh = id & 31, ord = id >> 5;
    const int chunk = 31 - ord;  // longest first
    const int b = bh >> 4, h = bh & 15;
    const int ktiles = chunk + 1;
    const int q0 = chunk * 64;
    const size_t headoff = ((size_t)(b * Hx + h)) * Tx * DHx;
    const __bf16* Kbase = K + headoff;   // [t][d]
    const __bf16* Vbase = Vt + headoff;  // [d][t]
    const int sr = t >> 2, sc = (t & 3) * 16;  // staging: 64 rows x 4x16 cols
    const int qg = q0 + wave * 16 + quad * 4;

    bf16x8 qf0, qf1;
    {
        const __bf16* Qp = Q + headoff + (size_t)(q0 + wave * 16 + lane15) * 64 + quad * 8;
        qf0 = *(const bf16x8*)Qp;
        qf1 = *(const bf16x8*)(Qp + 32);
    }
    f32x4 o[4];
#pragma unroll
    for (int i = 0; i < 4; i++) o[i] = (f32x4){0.f, 0.f, 0.f, 0.f};
    float lpart[4] = {0.f, 0.f, 0.f, 0.f};

    // prefetch tile 0 into regs
    bf16x8 kpre0, kpre1, vpre0, vpre1;
    {
        const __bf16* Kp = Kbase + (size_t)sr * 64 + sc;
        kpre0 = *(const bf16x8*)Kp; kpre1 = *(const bf16x8*)(Kp + 8);
        const __bf16* Vp = Vbase + (size_t)sr * Tx + sc;
        vpre0 = *(const bf16x8*)Vp; vpre1 = *(const bf16x8*)(Vp + 8);
    }

    for (int kt = 0; kt < ktiles; kt++) {
        __syncthreads();  // previous tile's reads complete before overwrite
        *(bf16x8*)&Ks[sr * 72 + sc] = kpre0;
        *(bf16x8*)&Ks[sr * 72 + sc + 8] = kpre1;
        *(bf16x8*)&Vs[sr * 72 + sc] = vpre0;
        *(bf16x8*)&Vs[sr * 72 + sc + 8] = vpre1;
        if (kt + 1 < ktiles) {  // next tile's global loads overlap compute
            const __bf16* Kp = Kbase + (size_t)((kt + 1) * 64 + sr) * 64 + sc;
            kpre0 = *(const bf16x8*)Kp; kpre1 = *(const bf16x8*)(Kp + 8);
            const __bf16* Vp = Vbase + (size_t)sr * Tx + (kt + 1) * 64 + sc;
            vpre0 = *(const bf16x8*)Vp; vpre1 = *(const bf16x8*)(Vp + 8);
        }
        __syncthreads();  // staged tile visible

        // S = Q K^T
        f32x4 s[4];
#pragma unroll
        for (int nt = 0; nt < 4; nt++) {
            s[nt] = (f32x4){0.f, 0.f, 0.f, 0.f};
            bf16x8 b0 = *(const bf16x8*)&Ks[(nt * 16 + lane15) * 72 + quad * 8];
            s[nt] = __builtin_amdgcn_mfma_f32_16x16x32_bf16(qf0, b0, s[nt], 0, 0, 0);
            bf16x8 b1 = *(const bf16x8*)&Ks[(nt * 16 + lane15) * 72 + 32 + quad * 8];
            s[nt] = __builtin_amdgcn_mfma_f32_16x16x32_bf16(qf1, b1, s[nt], 0, 0, 0);
        }

        // p = exp(s), causal mask; per-lane partial row-sums; P -> own-wave Ps rows
        const int kbase = kt * 64;
#pragma unroll
        for (int nt = 0; nt < 4; nt++)
#pragma unroll
            for (int reg = 0; reg < 4; reg++) {
                float e = __expf(s[nt][reg]);
                if (kbase + nt * 16 + lane15 > qg + reg) e = 0.f;
                lpart[reg] += e;
                Ps[(wave * 16 + quad * 4 + reg) * 80 + nt * 16 + lane15] = (__bf16)e;
            }

        // O += P V (own-wave Ps rows; lgkmcnt covers RAW)
        bf16x8 pa0 = *(const bf16x8*)&Ps[(wave * 16 + lane15) * 80 + quad * 8];
        bf16x8 pa1 = *(const bf16x8*)&Ps[(wave * 16 + lane15) * 80 + 32 + quad * 8];
#pragma unroll
        for (int dt = 0; dt < 4; dt++) {
            bf16x8 vb0 = *(const bf16x8*)&Vs[(dt * 16 + lane15) * 72 + quad * 8];
            o[dt] = __builtin_amdgcn_mfma_f32_16x16x32_bf16(pa0, vb0, o[dt], 0, 0, 0);
            bf16x8 vb1 = *(const bf16x8*)&Vs[(dt * 16 + lane15) * 72 + 32 + quad * 8];
            o[dt] = __builtin_amdgcn_mfma_f32_16x16x32_bf16(pa1, vb1, o[dt], 0, 0, 0);
        }
    }

    float inv[4];
#pragma unroll
    for (int reg = 0; reg < 4; reg++) {
        float l = lpart[reg];
#pragma unroll
        for (int off = 1; off < 16; off <<= 1) l += __shfl_xor(l, off);
        inv[reg] = 1.f / l;
    }
#pragma unroll
    for (int dt = 0; dt < 4; dt++)
#pragma unroll
        for (int reg = 0; reg < 4; reg++) {
            int q = q0 + wave * 16 + quad * 4 + reg;
            ctx[(((size_t)(b * Tx + q)) * Hx + h) * 64 + dt * 16 + lane15] =
                (__bf16)(o[dt][reg] * inv[reg]);
        }
}

extern "C" void kernel_launch(void* const* d_in, const int* in_sizes, int n_in,
                              void* d_out, int out_size, void* d_ws, size_t ws_size,
                              hipStream_t stream) {
    const float* x  = (const float*)d_in[0];
    const float* Wq = (const float*)d_in[1];
    const float* Wk = (const float*)d_in[2];
    const float* Wv = (const float*)d_in[3];
    const float* Wo = (const float*)d_in[4];
    const float* bo = (const float*)d_in[5];
    float* out = (float*)d_out;

    char* ws = (char*)d_ws;
    __bf16* xb  = (__bf16*)(ws + 0);                 // 8 MB
    __bf16* Wt  = (__bf16*)(ws + (8ull << 20));      // 4 x 2 MB
    __bf16* Qb  = (__bf16*)(ws + (16ull << 20));     // 8 MB [B,H,T,DH] (pre-scaled 1/8)
    __bf16* Kb  = (__bf16*)(ws + (24ull << 20));     // 8 MB [B,H,T,DH]
    __bf16* Vtg = (__bf16*)(ws + (32ull << 20));     // 8 MB [B,H,DH,T]
    __bf16* ctx = (__bf16*)(ws + (40ull << 20));     // 8 MB [B,T,H,DH]

    prep<<<dim3(16, 16, 5), 256, 0, stream>>>(x, Wq, Wk, Wv, Wo, xb, Wt);

    gemm_qkv<<<dim3(Bx * Tx / 64, 3 * Dx / 128), 256, 0, stream>>>(xb, Wt, Qb, Kb, Vtg);

    attn_mfma<<<dim3(1024), 256, 0, stream>>>(Qb, Kb, Vtg, ctx);

    gemm_out<<<dim3(Bx * Tx / 64, Dx / 64), 256, 0, stream>>>(ctx, Wt + 3 * (1u << 20), out, bo);
}

// Round 11
// 175.818 us; speedup vs baseline: 1.0696x; 1.0523x over previous
//
#include <hip/hip_runtime.h>
#include <hip/hip_bf16.h>

// MHA: B=2, T=2048, D=1024, H=16, DH=64. fp32 in/out, bf16 MFMA internal.
// R11: GEMM BK=64 via two BK=32 sub-tiles (gload16 mapping + stride-32 layout
//      preserved) -> K-step barrier count halves (32->16). attn/prep = R10.

typedef __bf16 bf16x8 __attribute__((ext_vector_type(8)));
typedef __bf16 bf16x4 __attribute__((ext_vector_type(4)));
typedef float  f32x4  __attribute__((ext_vector_type(4)));

#define Bx 2
#define Tx 2048
#define Dx 1024
#define Hx 16
#define DHx 64

// ---------------- prep: z=0 -> x fp32->bf16; z=1..4 -> W transpose+cvt ----------------
__global__ __launch_bounds__(256) void prep(const float* __restrict__ x,
                                            const float* __restrict__ W0,
                                            const float* __restrict__ W1,
                                            const float* __restrict__ W2,
                                            const float* __restrict__ W3,
                                            __bf16* __restrict__ xb,
                                            __bf16* __restrict__ Wt) {
    const int z = blockIdx.z;
    if (z == 0) {
        const int blk = blockIdx.y * 16 + blockIdx.x;
        const float* xp = x + (size_t)blk * 16384;
        __bf16* xo = xb + (size_t)blk * 16384;
#pragma unroll
        for (int i = 0; i < 16; i++) {
            float4 v = *(const float4*)(xp + i * 1024 + threadIdx.x * 4);
            bf16x4 o;
            o[0] = (__bf16)v.x; o[1] = (__bf16)v.y; o[2] = (__bf16)v.z; o[3] = (__bf16)v.w;
            *(bf16x4*)(xo + i * 1024 + threadIdx.x * 4) = o;
        }
        return;
    }
    __shared__ float tile[64][65];
    const float* W = (z == 1) ? W0 : (z == 2) ? W1 : (z == 3) ? W2 : W3;
    __bf16* o = Wt + (size_t)(z - 1) * Dx * Dx;
    int k0 = blockIdx.x * 64, n0 = blockIdx.y * 64;
    int t = threadIdx.x;
    int cc = t & 63, rbase = t >> 6;
#pragma unroll
    for (int i = 0; i < 16; i++) {
        int rr = rbase + i * 4;
        tile[rr][cc] = W[(size_t)(k0 + rr) * Dx + n0 + cc];
    }
    __syncthreads();
#pragma unroll
    for (int i = 0; i < 16; i++) {
        int rr = rbase + i * 4;
        o[(size_t)(n0 + rr) * Dx + k0 + cc] = (__bf16)tile[cc][rr];
    }
}

static __device__ __forceinline__ void gload16(const __bf16* g, __bf16* l) {
    __builtin_amdgcn_global_load_lds((const __attribute__((address_space(1))) void*)g,
                                     (__attribute__((address_space(3))) void*)l, 16, 0, 0);
}

// ---------------- fused QKV GEMM: [4096 x 3072] = xb @ [WqT;WkT;WvT]^T ----------------
// 64x128 tile, BK=64 as 2 BK=32 sub-tiles. Grid 64x24 = 1536 blocks = 6/CU (24 KB LDS).
__global__ __launch_bounds__(256, 6) void gemm_qkv(const __bf16* __restrict__ A,
                                                   const __bf16* __restrict__ BT,
                                                   __bf16* __restrict__ Qb,
                                                   __bf16* __restrict__ Kb,
                                                   __bf16* __restrict__ Vt) {
    __shared__ __bf16 As[2][64 * 32];   // 8 KB  (two k-halves)
    __shared__ __bf16 Bs[2][128 * 32];  // 16 KB
    const int t = threadIdx.x;
    const int lane = t & 63, wave = t >> 6;
    const int lane15 = lane & 15, quad = lane >> 4;
    const int m0 = blockIdx.x * 64, n0 = blockIdx.y * 128;
    const int wm = wave & 1, wn = wave >> 1;

    const int srA = wave * 16 + (lane >> 2), sc = (lane & 3) * 8;
    const int srB = wave * 32 + (lane >> 2);
    const __bf16* Ag = A + (size_t)(m0 + srA) * Dx + sc;
    const __bf16* Bg = BT + (size_t)(n0 + srB) * Dx + sc;
    __bf16* Asl0  = &As[0][(wave * 16) * 32];
    __bf16* Asl1  = &As[1][(wave * 16) * 32];
    __bf16* Bsl00 = &Bs[0][(wave * 32) * 32];
    __bf16* Bsl01 = &Bs[0][(wave * 32 + 16) * 32];
    __bf16* Bsl10 = &Bs[1][(wave * 32) * 32];
    __bf16* Bsl11 = &Bs[1][(wave * 32 + 16) * 32];

    f32x4 acc[2][4];
#pragma unroll
    for (int i = 0; i < 2; i++)
#pragma unroll
        for (int j = 0; j < 4; j++) acc[i][j] = (f32x4){0.f, 0.f, 0.f, 0.f};

    for (int k0 = 0; k0 < Dx; k0 += 64) {
        gload16(Ag, Asl0);
        gload16(Ag + 32, Asl1);
        gload16(Bg, Bsl00);
        gload16(Bg + 16 * Dx, Bsl01);
        gload16(Bg + 32, Bsl10);
        gload16(Bg + 32 + 16 * Dx, Bsl11);
        Ag += 64; Bg += 64;
        __syncthreads();
#pragma unroll
        for (int half = 0; half < 2; half++) {
            bf16x8 af[2], bf[4];
#pragma unroll
            for (int i = 0; i < 2; i++)
                af[i] = *(const bf16x8*)&As[half][(wm * 32 + i * 16 + lane15) * 32 + quad * 8];
#pragma unroll
            for (int j = 0; j < 4; j++)
                bf[j] = *(const bf16x8*)&Bs[half][(wn * 64 + j * 16 + lane15) * 32 + quad * 8];
#pragma unroll
            for (int mt = 0; mt < 2; mt++)
#pragma unroll
                for (int nt = 0; nt < 4; nt++)
                    acc[mt][nt] = __builtin_amdgcn_mfma_f32_16x16x32_bf16(af[mt], bf[nt], acc[mt][nt], 0, 0, 0);
        }
        __syncthreads();
    }

    const int z = n0 >> 10;  // block n-range lies in one z (128 | 1024)
    if (z < 2) {
        __bf16* outp = z ? Kb : Qb;
        const float scale = z ? 1.0f : 0.125f;
#pragma unroll
        for (int mt = 0; mt < 2; mt++)
#pragma unroll
            for (int nt = 0; nt < 4; nt++) {
                const int cc = (n0 + wn * 64 + nt * 16 + lane15) & 1023;
                const int h = cc >> 6, dh = cc & 63;
#pragma unroll
                for (int r4 = 0; r4 < 4; r4++) {
                    const int row = m0 + wm * 32 + mt * 16 + quad * 4 + r4;
                    const int b = row >> 11, tt = row & 2047;
                    outp[(((size_t)(b * Hx + h) * Tx + tt) << 6) + dh] =
                        (__bf16)(acc[mt][nt][r4] * scale);
                }
            }
    } else {
#pragma unroll
        for (int mt = 0; mt < 2; mt++)
#pragma unroll
            for (int nt = 0; nt < 4; nt++) {
                const int cc = (n0 + wn * 64 + nt * 16 + lane15) & 1023;
                const int h = cc >> 6, dh = cc & 63;
#pragma unroll
                for (int r4 = 0; r4 < 4; r4++) {
                    const int row = m0 + wm * 32 + mt * 16 + quad * 4 + r4;
                    const int b = row >> 11, tt = row & 2047;
                    Vt[((size_t)(b * Hx + h) * DHx + dh) * Tx + tt] = (__bf16)acc[mt][nt][r4];
                }
            }
    }
}

// ---------------- output GEMM: out[4096 x 1024] = ctx @ Wo + bo ----------------
// 64x64 tile, BK=64 as 2 BK=32 sub-tiles. Grid 64x16 = 1024 blocks = 4/CU (16 KB LDS).
__global__ __launch_bounds__(256, 4) void gemm_out(const __bf16* __restrict__ A,
                                                   const __bf16* __restrict__ BT,
                                                   float* __restrict__ outf,
                                                   const float* __restrict__ bias) {
    __shared__ __bf16 As[2][64 * 32];
    __shared__ __bf16 Bs[2][64 * 32];
    const int t = threadIdx.x;
    const int lane = t & 63, wave = t >> 6;
    const int lane15 = lane & 15, quad = lane >> 4;
    const int m0 = blockIdx.x * 64, n0 = blockIdx.y * 64;
    const int wm = wave & 1, wn = wave >> 1;

    const int sr = wave * 16 + (lane >> 2), sc = (lane & 3) * 8;
    const __bf16* Ag = A + (size_t)(m0 + sr) * Dx + sc;
    const __bf16* Bg = BT + (size_t)(n0 + sr) * Dx + sc;
    __bf16* Asl0 = &As[0][(wave * 16) * 32];
    __bf16* Asl1 = &As[1][(wave * 16) * 32];
    __bf16* Bsl0 = &Bs[0][(wave * 16) * 32];
    __bf16* Bsl1 = &Bs[1][(wave * 16) * 32];

    f32x4 acc[2][2];
#pragma unroll
    for (int i = 0; i < 2; i++)
#pragma unroll
        for (int j = 0; j < 2; j++) acc[i][j] = (f32x4){0.f, 0.f, 0.f, 0.f};

    for (int k0 = 0; k0 < Dx; k0 += 64) {
        gload16(Ag, Asl0);
        gload16(Ag + 32, Asl1);
        gload16(Bg, Bsl0);
        gload16(Bg + 32, Bsl1);
        Ag += 64; Bg += 64;
        __syncthreads();
#pragma unroll
        for (int half = 0; half < 2; half++) {
            bf16x8 af[2], bf[2];
#pragma unroll
            for (int i = 0; i < 2; i++) {
                af[i] = *(const bf16x8*)&As[half][(wm * 32 + i * 16 + lane15) * 32 + quad * 8];
                bf[i] = *(const bf16x8*)&Bs[half][(wn * 32 + i * 16 + lane15) * 32 + quad * 8];
            }
#pragma unroll
            for (int mt = 0; mt < 2; mt++)
#pragma unroll
                for (int nt = 0; nt < 2; nt++)
                    acc[mt][nt] = __builtin_amdgcn_mfma_f32_16x16x32_bf16(af[mt], bf[nt], acc[mt][nt], 0, 0, 0);
        }
        __syncthreads();
    }

#pragma unroll
    for (int mt = 0; mt < 2; mt++)
#pragma unroll
        for (int nt = 0; nt < 2; nt++) {
            const int col = n0 + wn * 32 + nt * 16 + lane15;
#pragma unroll
            for (int r4 = 0; r4 < 4; r4++) {
                const int row = m0 + wm * 32 + mt * 16 + quad * 4 + r4;
                outf[(size_t)row * Dx + col] = acc[mt][nt][r4] + bias[col];
            }
        }
}

// ---------------- MFMA flash attention: 1 chunk/block, 4/CU, XCD-pinned ----------------
__global__ __launch_bounds__(256) void attn_mfma(const __bf16* __restrict__ Q,
                                                 const __bf16* __restrict__ K,
                                                 const __bf16* __restrict__ Vt,
                                                 __bf16* __restrict__ ctx) {
    __shared__ __bf16 Ks[64 * 72];   // [key][d]   9 KB
    __shared__ __bf16 Vs[64 * 72];   // [d][key]   9 KB
    __shared__ __bf16 Ps[64 * 80];   // [q][key]  10 KB
    const int t = threadIdx.x;
    const int lane = t & 63, wave = t >> 6;
    const int lane15 = lane & 15, quad = lane >> 4;
    const int id = blockIdx.x;
    const int bh = id & 31, ord = id >> 5;
    const int chunk = 31 - ord;  // longest first
    const int b = bh >> 4, h = bh & 15;
    const int ktiles = chunk + 1;
    const int q0 = chunk * 64;
    const size_t headoff = ((size_t)(b * Hx + h)) * Tx * DHx;
    const __bf16* Kbase = K + headoff;   // [t][d]
    const __bf16* Vbase = Vt + headoff;  // [d][t]
    const int sr = t >> 2, sc = (t & 3) * 16;
    const int qg = q0 + wave * 16 + quad * 4;

    bf16x8 qf0, qf1;
    {
        const __bf16* Qp = Q + headoff + (size_t)(q0 + wave * 16 + lane15) * 64 + quad * 8;
        qf0 = *(const bf16x8*)Qp;
        qf1 = *(const bf16x8*)(Qp + 32);
    }
    f32x4 o[4];
#pragma unroll
    for (int i = 0; i < 4; i++) o[i] = (f32x4){0.f, 0.f, 0.f, 0.f};
    float lpart[4] = {0.f, 0.f, 0.f, 0.f};

    bf16x8 kpre0, kpre1, vpre0, vpre1;
    {
        const __bf16* Kp = Kbase + (size_t)sr * 64 + sc;
        kpre0 = *(const bf16x8*)Kp; kpre1 = *(const bf16x8*)(Kp + 8);
        const __bf16* Vp = Vbase + (size_t)sr * Tx + sc;
        vpre0 = *(const bf16x8*)Vp; vpre1 = *(const bf16x8*)(Vp + 8);
    }

    for (int kt = 0; kt < ktiles; kt++) {
        __syncthreads();
        *(bf16x8*)&Ks[sr * 72 + sc] = kpre0;
        *(bf16x8*)&Ks[sr * 72 + sc + 8] = kpre1;
        *(bf16x8*)&Vs[sr * 72 + sc] = vpre0;
        *(bf16x8*)&Vs[sr * 72 + sc + 8] = vpre1;
        if (kt + 1 < ktiles) {
            const __bf16* Kp = Kbase + (size_t)((kt + 1) * 64 + sr) * 64 + sc;
            kpre0 = *(const bf16x8*)Kp; kpre1 = *(const bf16x8*)(Kp + 8);
            const __bf16* Vp = Vbase + (size_t)sr * Tx + (kt + 1) * 64 + sc;
            vpre0 = *(const bf16x8*)Vp; vpre1 = *(const bf16x8*)(Vp + 8);
        }
        __syncthreads();

        f32x4 s[4];
#pragma unroll
        for (int nt = 0; nt < 4; nt++) {
            s[nt] = (f32x4){0.f, 0.f, 0.f, 0.f};
            bf16x8 b0 = *(const bf16x8*)&Ks[(nt * 16 + lane15) * 72 + quad * 8];
            s[nt] = __builtin_amdgcn_mfma_f32_16x16x32_bf16(qf0, b0, s[nt], 0, 0, 0);
            bf16x8 b1 = *(const bf16x8*)&Ks[(nt * 16 + lane15) * 72 + 32 + quad * 8];
            s[nt] = __builtin_amdgcn_mfma_f32_16x16x32_bf16(qf1, b1, s[nt], 0, 0, 0);
        }

        const int kbase = kt * 64;
#pragma unroll
        for (int nt = 0; nt < 4; nt++)
#pragma unroll
            for (int reg = 0; reg < 4; reg++) {
                float e = __expf(s[nt][reg]);
                if (kbase + nt * 16 + lane15 > qg + reg) e = 0.f;
                lpart[reg] += e;
                Ps[(wave * 16 + quad * 4 + reg) * 80 + nt * 16 + lane15] = (__bf16)e;
            }

        bf16x8 pa0 = *(const bf16x8*)&Ps[(wave * 16 + lane15) * 80 + quad * 8];
        bf16x8 pa1 = *(const bf16x8*)&Ps[(wave * 16 + lane15) * 80 + 32 + quad * 8];
#pragma unroll
        for (int dt = 0; dt < 4; dt++) {
            bf16x8 vb0 = *(const bf16x8*)&Vs[(dt * 16 + lane15) * 72 + quad * 8];
            o[dt] = __builtin_amdgcn_mfma_f32_16x16x32_bf16(pa0, vb0, o[dt], 0, 0, 0);
            bf16x8 vb1 = *(const bf16x8*)&Vs[(dt * 16 + lane15) * 72 + 32 + quad * 8];
            o[dt] = __builtin_amdgcn_mfma_f32_16x16x32_bf16(pa1, vb1, o[dt], 0, 0, 0);
        }
    }

    float inv[4];
#pragma unroll
    for (int reg = 0; reg < 4; reg++) {
        float l = lpart[reg];
#pragma unroll
        for (int off = 1; off < 16; off <<= 1) l += __shfl_xor(l, off);
        inv[reg] = 1.f / l;
    }
#pragma unroll
    for (int dt = 0; dt < 4; dt++)
#pragma unroll
        for (int reg = 0; reg < 4; reg++) {
            int q = q0 + wave * 16 + quad * 4 + reg;
            ctx[(((size_t)(b * Tx + q)) * Hx + h) * 64 + dt * 16 + lane15] =
                (__bf16)(o[dt][reg] * inv[reg]);
        }
}

extern "C" void kernel_launch(void* const* d_in, const int* in_sizes, int n_in,
                              void* d_out, int out_size, void* d_ws, size_t ws_size,
                              hipStream_t stream) {
    const float* x  = (const float*)d_in[0];
    const float* Wq = (const float*)d_in[1];
    const float* Wk = (const float*)d_in[2];
    const float* Wv = (const float*)d_in[3];
    const float* Wo = (const float*)d_in[4];
    const float* bo = (const float*)d_in[5];
    float* out = (float*)d_out;

    char* ws = (char*)d_ws;
    __bf16* xb  = (__bf16*)(ws + 0);                 // 8 MB
    __bf16* Wt  = (__bf16*)(ws + (8ull << 20));      // 4 x 2 MB
    __bf16* Qb  = (__bf16*)(ws + (16ull << 20));     // 8 MB [B,H,T,DH] (pre-scaled 1/8)
    __bf16* Kb  = (__bf16*)(ws + (24ull << 20));     // 8 MB [B,H,T,DH]
    __bf16* Vtg = (__bf16*)(ws + (32ull << 20));     // 8 MB [B,H,DH,T]
    __bf16* ctx = (__bf16*)(ws + (40ull << 20));     // 8 MB [B,T,H,DH]

    prep<<<dim3(16, 16, 5), 256, 0, stream>>>(x, Wq, Wk, Wv, Wo, xb, Wt);

    gemm_qkv<<<dim3(Bx * Tx / 64, 3 * Dx / 128), 256, 0, stream>>>(xb, Wt, Qb, Kb, Vtg);

    attn_mfma<<<dim3(1024), 256, 0, stream>>>(Qb, Kb, Vtg, ctx);

    gemm_out<<<dim3(Bx * Tx / 64, Dx / 64), 256, 0, stream>>>(ctx, Wt + 3 * (1u << 20), out, bo);
}